// Round 11
// baseline (555.420 us; speedup 1.0000x reference)
//
#include <hip/hip_runtime.h>
#include <cstdint>
#include <cstddef>

#define L_ 2048
#define D_ 128
#define B_ 32
#define NT_ 32   // kv tiles of 64

static constexpr float SCALE = 0.08838834764831845f;  // 1/sqrt(128)
static constexpr float LOG2E = 1.4426950408889634f;
static constexpr float THR_  = 8.0f;                  // defer-rescale threshold

typedef __bf16 bf16x8 __attribute__((ext_vector_type(8)));
typedef __bf16 bf16x4 __attribute__((ext_vector_type(4)));
typedef float  f32x4  __attribute__((ext_vector_type(4)));
typedef int    i32x4  __attribute__((ext_vector_type(4)));

typedef const __attribute__((address_space(1))) uint32_t* gas_t;
typedef __attribute__((address_space(3))) uint32_t*       las_t;

__device__ __forceinline__ void dma16(const void* g, void* l) {
  __builtin_amdgcn_global_load_lds((gas_t)g, (las_t)l, 16, 0, 0);
}

// PV k-permutation (see r7): P stays in registers; V image columns permuted.
__device__ __forceinline__ int cperm(int r) {
  return (r & 32) | (((r >> 3) & 1) << 4) | (((r >> 2) & 1) << 3)
       | (((r >> 4) & 1) << 2) | (r & 3);
}

// ---------------------------------------------------------------------------
// prep_kv: bf16 K (QK-swizzled) and V^T (cperm + swizzle) tile images so a
// linear DMA reproduces the LDS layouts. grid 1024 x 256. (unchanged)
// ---------------------------------------------------------------------------
__global__ __launch_bounds__(256) void prep_kv(
    const float* __restrict__ K, const float* __restrict__ V,
    __bf16* __restrict__ gK, __bf16* __restrict__ gVt)
{
  const int b   = blockIdx.x >> 5;
  const int kt  = blockIdx.x & 31;
  const int tid = threadIdx.x;
  const size_t tile = ((size_t)b * NT_ + kt) * 8192;

#pragma unroll
  for (int i = 0; i < 4; ++i) {
    const int g  = tid + i * 256;
    const int r  = g >> 4;
    const int c  = g & 15;
    const int d0 = (c ^ (r & 7)) * 8;
    const float* src = K + ((size_t)b * L_ + kt * 64 + r) * D_ + d0;
    float4 a = *(const float4*)src;
    float4 e = *(const float4*)(src + 4);
    bf16x8 f;
    f[0]=(__bf16)a.x; f[1]=(__bf16)a.y; f[2]=(__bf16)a.z; f[3]=(__bf16)a.w;
    f[4]=(__bf16)e.x; f[5]=(__bf16)e.y; f[6]=(__bf16)e.z; f[7]=(__bf16)e.w;
    *(bf16x8*)((char*)(gK + tile) + r * 256 + c * 16) = f;
  }

  __shared__ alignas(16) __bf16 Vt[8192];
  char* vb = (char*)Vt;
  const int vr     = tid & 63;
  const int vc     = cperm(vr);
  const int vdbase = (tid >> 6) * 32;
  const float* vrow = V + ((size_t)b * L_ + kt * 64 + vr) * D_ + vdbase;
#pragma unroll
  for (int c = 0; c < 8; ++c) {
    float4 v4 = *(const float4*)(vrow + c * 4);
    const int d0 = vdbase + c * 4;
    float vv[4] = {v4.x, v4.y, v4.z, v4.w};
#pragma unroll
    for (int jj = 0; jj < 4; ++jj) {
      const int d = d0 + jj;
      *(__bf16*)(vb + d * 128 + ((vc * 2) ^ ((d & 7) << 4))) = (__bf16)vv[jj];
    }
  }
  __syncthreads();
#pragma unroll
  for (int i = 0; i < 4; ++i) {
    const int off = (tid + i * 256) * 16;
    *(i32x4*)((char*)(gVt + tile) + off) = *(const i32x4*)(vb + off);
  }
}

// ---------------------------------------------------------------------------
// attn_fwd<SPLIT, MODE>: 32 q-rows per wave (2 halves share every kf/vf LDS
// read), 256 threads (4 waves, QBLK=128), single-buffer 32KB LDS.
//   SPLIT=1: grid 1024 = (half, b, qblk); each block does 16 kv tiles and
//            stores raw O + (m,l) to workspace -> 4 blocks/CU = 16 waves/CU
//            WITH 2x LDS reuse (the r6-r9 plateau breaker).
//   SPLIT=0: grid 512, full kv range, normalized epilogue + fused attn0 norm.
//   MODE 1: DMA staging from prepped images.  MODE 0: in-kernel staging.
// ---------------------------------------------------------------------------
template<int SPLIT, int MODE>
__global__ __launch_bounds__(256, 4) void attn_fwd(
    const float* __restrict__ Q, const float* __restrict__ K,
    const float* __restrict__ V, const float* __restrict__ bias,
    const __bf16* __restrict__ gK, const __bf16* __restrict__ gVt,
    float* __restrict__ ctx, float* __restrict__ attn0,
    float* __restrict__ Opart, float2* __restrict__ ml)
{
  const int id = blockIdx.x;
  int half, b, qblk;
  if constexpr (SPLIT) {
    half = id >> 9;                 // 0..1
    const int rem = id & 511;
    b    = rem >> 4;                // 0..31
    qblk = rem & 15;                // 0..15  (XCD = id%8 ~ qblk%8: b==0 spread)
  } else {
    half = 0; b = id >> 4; qblk = id & 15;
  }
  const int kt0 = SPLIT ? half * (NT_ / 2) : 0;
  const int ktN = SPLIT ? kt0 + (NT_ / 2) : NT_;

  const int tid  = threadIdx.x;
  const int wave = tid >> 6;
  const int lane = tid & 63;
  const int lg   = lane >> 4;
  const int lr   = lane & 15;

  const int qbase = qblk * 128 + wave * 32;

  __shared__ alignas(16) __bf16 Ksh[8192];    // 16 KB single buffer
  __shared__ alignas(16) __bf16 Vtsh[8192];   // 16 KB single buffer
  const char* kb = (const char*)Ksh;
  const char* vb = (const char*)Vtsh;

  // ---- Q fragments for both 16-row halves, pre-scaled ----
  bf16x8 qf0[4], qf1[4];
#pragma unroll
  for (int h = 0; h < 2; ++h) {
    const float* qrow = Q + ((size_t)b * L_ + (qbase + h * 16 + lr)) * D_;
#pragma unroll
    for (int kc = 0; kc < 4; ++kc) {
      const int d0 = kc * 32 + lg * 8;
      float4 a = *(const float4*)(qrow + d0);
      float4 c = *(const float4*)(qrow + d0 + 4);
      bf16x8 f;
      f[0] = (__bf16)(a.x * SCALE); f[1] = (__bf16)(a.y * SCALE);
      f[2] = (__bf16)(a.z * SCALE); f[3] = (__bf16)(a.w * SCALE);
      f[4] = (__bf16)(c.x * SCALE); f[5] = (__bf16)(c.y * SCALE);
      f[6] = (__bf16)(c.z * SCALE); f[7] = (__bf16)(c.w * SCALE);
      if (h == 0) qf0[kc] = f; else qf1[kc] = f;
    }
  }

  f32x4 O0[8], O1[8];
#pragma unroll
  for (int i = 0; i < 8; ++i) {
    O0[i] = (f32x4){0.f, 0.f, 0.f, 0.f};
    O1[i] = (f32x4){0.f, 0.f, 0.f, 0.f};
  }
  float m0 = -3.0e38f, m1 = -3.0e38f;
  float lp0 = 0.f, lp1 = 0.f;

  auto stage_dma = [&](int kt) {
    const char* gk = (const char*)(gK + ((size_t)b * NT_ + kt) * 8192);
    const char* gv = (const char*)(gVt + ((size_t)b * NT_ + kt) * 8192);
#pragma unroll
    for (int i = 0; i < 4; ++i) {
      const int off = (wave * 4 + i) * 1024;
      dma16(gk + off + lane * 16, (char*)Ksh + off);
      dma16(gv + off + lane * 16, (char*)Vtsh + off);
    }
  };

  float4 bA[4], bB[4];
  auto load_bias = [&](int kvbase) {
    const float* p0 = bias + (size_t)(qbase + lr) * L_ + kvbase + lg * 4;
    const float* p1 = p0 + (size_t)16 * L_;
#pragma unroll
    for (int t = 0; t < 4; ++t) {
      bA[t] = *(const float4*)(p0 + t * 16);
      bB[t] = *(const float4*)(p1 + t * 16);
    }
  };

  if constexpr (MODE >= 1) { stage_dma(kt0); load_bias(kt0 * 64); }

  for (int kt = kt0; kt < ktN; ++kt) {
    const int kvbase = kt * 64;

    if constexpr (MODE == 0) {
      // in-kernel staging (prev end-barrier protects the buffer)
#pragma unroll
      for (int it = 0; it < 8; ++it) {
        const int g  = tid + it * 256;
        const int r  = g >> 5;
        const int d0 = (g & 31) * 4;
        const size_t src = ((size_t)b * L_ + (kvbase + r)) * D_ + d0;
        float4 kv4 = *(const float4*)(K + src);
        bf16x4 k4 = {(__bf16)kv4.x, (__bf16)kv4.y, (__bf16)kv4.z, (__bf16)kv4.w};
        *(bf16x4*)((char*)Ksh + r * 256 + ((d0 * 2) ^ ((r & 7) << 4))) = k4;
      }
      {
        const int vr = tid & 63;
        const int vc = cperm(vr);
        const int vdbase = (tid >> 6) * 32;
        const float* vrow = V + ((size_t)b * L_ + (kvbase + vr)) * D_ + vdbase;
#pragma unroll
        for (int c = 0; c < 8; ++c) {
          float4 v4 = *(const float4*)(vrow + c * 4);
          const int d0 = vdbase + c * 4;
          float vv[4] = {v4.x, v4.y, v4.z, v4.w};
#pragma unroll
          for (int jj = 0; jj < 4; ++jj) {
            const int d = d0 + jj;
            *(__bf16*)((char*)Vtsh + d * 128 + ((vc * 2) ^ ((d & 7) << 4))) = (__bf16)vv[jj];
          }
        }
      }
    }
    __syncthreads();            // staging (DMA or in-kernel) complete
    if constexpr (MODE == 0) load_bias(kvbase);

    // ---- S^T = K.(SCALE*Q)^T for both halves; kf read ONCE, used twice ----
    f32x4 S0[4], S1[4];
#pragma unroll
    for (int t = 0; t < 4; ++t) {
      S0[t] = (f32x4){0.f, 0.f, 0.f, 0.f};
      S1[t] = (f32x4){0.f, 0.f, 0.f, 0.f};
    }
    __builtin_amdgcn_s_setprio(1);
#pragma unroll
    for (int t = 0; t < 4; ++t) {
      const int r   = t * 16 + lr;
      const int swz = (r & 7) << 4;
#pragma unroll
      for (int kc = 0; kc < 4; ++kc) {
        const int d0 = kc * 32 + lg * 8;
        bf16x8 kf = *(const bf16x8*)(kb + r * 256 + ((d0 * 2) ^ swz));
        S0[t] = __builtin_amdgcn_mfma_f32_16x16x32_bf16(kf, qf0[kc], S0[t], 0, 0, 0);
        S1[t] = __builtin_amdgcn_mfma_f32_16x16x32_bf16(kf, qf1[kc], S1[t], 0, 0, 0);
      }
    }
    __builtin_amdgcn_s_setprio(0);

    // ---- z = S + bias*SCALE ----
#pragma unroll
    for (int t = 0; t < 4; ++t) {
      S0[t][0] = fmaf(bA[t].x, SCALE, S0[t][0]); S0[t][1] = fmaf(bA[t].y, SCALE, S0[t][1]);
      S0[t][2] = fmaf(bA[t].z, SCALE, S0[t][2]); S0[t][3] = fmaf(bA[t].w, SCALE, S0[t][3]);
      S1[t][0] = fmaf(bB[t].x, SCALE, S1[t][0]); S1[t][1] = fmaf(bB[t].y, SCALE, S1[t][1]);
      S1[t][2] = fmaf(bB[t].z, SCALE, S1[t][2]); S1[t][3] = fmaf(bB[t].w, SCALE, S1[t][3]);
    }
    if (b == 0) {
      float* a0 = attn0 + (size_t)(qbase + lr) * L_ + kvbase + lg * 4;
      float* a1 = a0 + (size_t)16 * L_;
#pragma unroll
      for (int t = 0; t < 4; ++t) {
        *(float4*)(a0 + t * 16) = make_float4(S0[t][0], S0[t][1], S0[t][2], S0[t][3]);
        *(float4*)(a1 + t * 16) = make_float4(S1[t][0], S1[t][1], S1[t][2], S1[t][3]);
      }
    }

    // ---- online softmax per half ----
    float mt0 = fmaxf(fmaxf(fmaxf(S0[0][0], S0[0][1]), fmaxf(S0[0][2], S0[0][3])),
                      fmaxf(fmaxf(S0[1][0], S0[1][1]), fmaxf(S0[1][2], S0[1][3])));
    mt0 = fmaxf(mt0, fmaxf(fmaxf(S0[2][0], S0[2][1]), fmaxf(S0[2][2], S0[2][3])));
    mt0 = fmaxf(mt0, fmaxf(fmaxf(S0[3][0], S0[3][1]), fmaxf(S0[3][2], S0[3][3])));
    mt0 = fmaxf(mt0, __shfl_xor(mt0, 16));
    mt0 = fmaxf(mt0, __shfl_xor(mt0, 32));
    float mt1 = fmaxf(fmaxf(fmaxf(S1[0][0], S1[0][1]), fmaxf(S1[0][2], S1[0][3])),
                      fmaxf(fmaxf(S1[1][0], S1[1][1]), fmaxf(S1[1][2], S1[1][3])));
    mt1 = fmaxf(mt1, fmaxf(fmaxf(S1[2][0], S1[2][1]), fmaxf(S1[2][2], S1[2][3])));
    mt1 = fmaxf(mt1, fmaxf(fmaxf(S1[3][0], S1[3][1]), fmaxf(S1[3][2], S1[3][3])));
    mt1 = fmaxf(mt1, __shfl_xor(mt1, 16));
    mt1 = fmaxf(mt1, __shfl_xor(mt1, 32));

    if (__any((mt0 > m0 + THR_) || (mt1 > m1 + THR_))) {
      const float n0 = fmaxf(m0, mt0), c0 = exp2f((m0 - n0) * LOG2E);
      const float n1 = fmaxf(m1, mt1), c1 = exp2f((m1 - n1) * LOG2E);
      m0 = n0; m1 = n1; lp0 *= c0; lp1 *= c1;
      float cR0[4], cR1[4];
#pragma unroll
      for (int j = 0; j < 4; ++j) {
        cR0[j] = __shfl(c0, (lane & 0x30) | (lg * 4 + j));
        cR1[j] = __shfl(c1, (lane & 0x30) | (lg * 4 + j));
      }
#pragma unroll
      for (int dt = 0; dt < 8; ++dt) {
        O0[dt][0] *= cR0[0]; O0[dt][1] *= cR0[1]; O0[dt][2] *= cR0[2]; O0[dt][3] *= cR0[3];
        O1[dt][0] *= cR1[0]; O1[dt][1] *= cR1[1]; O1[dt][2] *= cR1[2]; O1[dt][3] *= cR1[3];
      }
    }

    // ---- P = exp(z - m) as bf16 ----
    bf16x4 pb0[4], pb1[4];
    const float mh0 = m0 * LOG2E, mh1 = m1 * LOG2E;
#pragma unroll
    for (int t = 0; t < 4; ++t) {
#pragma unroll
      for (int j = 0; j < 4; ++j) {
        const float p0 = exp2f(fmaf(S0[t][j], LOG2E, -mh0));
        const float p1 = exp2f(fmaf(S1[t][j], LOG2E, -mh1));
        lp0 += p0; lp1 += p1;
        pb0[t][j] = (__bf16)p0; pb1[t][j] = (__bf16)p1;
      }
    }

    // ---- O += P.V  (vf read ONCE, used twice; zero-shuffle pa) ----
    __builtin_amdgcn_s_setprio(1);
#pragma unroll
    for (int kc2 = 0; kc2 < 2; ++kc2) {
      bf16x8 pa0, pa1;
      pa0[0] = pb0[kc2*2][0];   pa0[1] = pb0[kc2*2][1];
      pa0[2] = pb0[kc2*2][2];   pa0[3] = pb0[kc2*2][3];
      pa0[4] = pb0[kc2*2+1][0]; pa0[5] = pb0[kc2*2+1][1];
      pa0[6] = pb0[kc2*2+1][2]; pa0[7] = pb0[kc2*2+1][3];
      pa1[0] = pb1[kc2*2][0];   pa1[1] = pb1[kc2*2][1];
      pa1[2] = pb1[kc2*2][2];   pa1[3] = pb1[kc2*2][3];
      pa1[4] = pb1[kc2*2+1][0]; pa1[5] = pb1[kc2*2+1][1];
      pa1[6] = pb1[kc2*2+1][2]; pa1[7] = pb1[kc2*2+1][3];
      const int c0 = kc2 * 32;
#pragma unroll
      for (int dt = 0; dt < 8; ++dt) {
        const int d = dt * 16 + lr;
        bf16x8 vf = *(const bf16x8*)(vb + d * 128 + (((c0 + lg * 8) * 2) ^ ((d & 7) << 4)));
        O0[dt] = __builtin_amdgcn_mfma_f32_16x16x32_bf16(pa0, vf, O0[dt], 0, 0, 0);
        O1[dt] = __builtin_amdgcn_mfma_f32_16x16x32_bf16(pa1, vf, O1[dt], 0, 0, 0);
      }
    }
    __builtin_amdgcn_s_setprio(0);

    __syncthreads();            // all reads done -> buffer reusable
    if constexpr (MODE >= 1) {
      if (kt + 1 < ktN) { load_bias((kt + 1) * 64); stage_dma(kt + 1); }
    }
  }

  // ---- epilogue ----
  float ls0 = lp0; ls0 += __shfl_xor(ls0, 16); ls0 += __shfl_xor(ls0, 32);
  float ls1 = lp1; ls1 += __shfl_xor(ls1, 16); ls1 += __shfl_xor(ls1, 32);

  if constexpr (SPLIT) {
    // store raw partials + per-row (m, l)
    float* Obase = Opart + ((size_t)half * B_ + b) * L_ * D_;
#pragma unroll
    for (int dt = 0; dt < 8; ++dt) {
      const int d = dt * 16 + lr;
#pragma unroll
      for (int j = 0; j < 4; ++j) {
        const int q0 = qbase + lg * 4 + j;
        Obase[(size_t)q0 * D_ + d]        = O0[dt][j];
        Obase[(size_t)(q0 + 16) * D_ + d] = O1[dt][j];
      }
    }
    if (lg == 0) {
      float2* mlb = ml + ((size_t)half * B_ + b) * L_;
      mlb[qbase + lr]      = make_float2(m0, ls0);
      mlb[qbase + 16 + lr] = make_float2(m1, ls1);
    }
  } else {
    const float li0 = 1.f / ls0, li1 = 1.f / ls1;
    float iR0[4], iR1[4];
#pragma unroll
    for (int j = 0; j < 4; ++j) {
      iR0[j] = __shfl(li0, (lane & 0x30) | (lg * 4 + j));
      iR1[j] = __shfl(li1, (lane & 0x30) | (lg * 4 + j));
    }
#pragma unroll
    for (int dt = 0; dt < 8; ++dt) {
      const int d = dt * 16 + lr;
#pragma unroll
      for (int j = 0; j < 4; ++j) {
        const int q0 = qbase + lg * 4 + j;
        ctx[((size_t)b * L_ + q0) * D_ + d]        = O0[dt][j] * iR0[j];
        ctx[((size_t)b * L_ + q0 + 16) * D_ + d]   = O1[dt][j] * iR1[j];
      }
    }
    if (b == 0) {   // fused attn0 normalize (rows owned by this wave)
#pragma unroll 1
      for (int rr = 0; rr < 32; ++rr) {
        const float mr = __shfl(rr < 16 ? m0 : m1, rr & 15) * LOG2E;
        const float iv = __shfl(rr < 16 ? li0 : li1, rr & 15);
        float4* rowp = (float4*)(attn0 + (size_t)(qbase + rr) * L_);
#pragma unroll
        for (int c = 0; c < 8; ++c) {
          float4 v = rowp[c * 64 + lane];
          v.x = exp2f(fmaf(v.x, LOG2E, -mr)) * iv;
          v.y = exp2f(fmaf(v.y, LOG2E, -mr)) * iv;
          v.z = exp2f(fmaf(v.z, LOG2E, -mr)) * iv;
          v.w = exp2f(fmaf(v.w, LOG2E, -mr)) * iv;
          rowp[c * 64 + lane] = v;
        }
      }
    }
  }
}

// ---------------------------------------------------------------------------
// combine: ctx = (O0*w0 + O1*w1) / (l0*w0 + l1*w1), wi = exp(mi - m).
// grid 8192 x 256: block = 8 rows x 32 lanes (one float4 each).
// ---------------------------------------------------------------------------
__global__ __launch_bounds__(256) void combine(
    const float* __restrict__ Opart, const float2* __restrict__ ml,
    float* __restrict__ ctx)
{
  const int r = blockIdx.x * 8 + (threadIdx.x >> 5);   // flat (b*L + q)
  const int c = threadIdx.x & 31;
  const float2 a = ml[r];
  const float2 e = ml[(size_t)B_ * L_ + r];
  const float m  = fmaxf(a.x, e.x);
  float w0 = exp2f((a.x - m) * LOG2E);
  float w1 = exp2f((e.x - m) * LOG2E);
  const float inv = 1.f / (a.y * w0 + e.y * w1);
  w0 *= inv; w1 *= inv;
  const float4 x = ((const float4*)Opart)[(size_t)r * 32 + c];
  const float4 y = ((const float4*)(Opart + (size_t)B_ * L_ * D_))[(size_t)r * 32 + c];
  float4 o = {x.x * w0 + y.x * w1, x.y * w0 + y.y * w1,
              x.z * w0 + y.z * w1, x.w * w0 + y.w * w1};
  ((float4*)ctx)[(size_t)r * 32 + c] = o;
}

// ---------------------------------------------------------------------------
// attn0_norm: P = exp(z - m) / l with global (m, l) from the two halves.
// grid 2048 rows x 256 thr (batch-0 rows are ml[0..L) and ml[B*L..B*L+L)).
// ---------------------------------------------------------------------------
__global__ __launch_bounds__(256) void attn0_norm(
    float* __restrict__ attn0, const float2* __restrict__ ml)
{
  const int row = blockIdx.x;
  const float2 a = ml[row];
  const float2 e = ml[(size_t)B_ * L_ + row];
  const float m  = fmaxf(a.x, e.x);
  const float l  = a.y * exp2f((a.x - m) * LOG2E) + e.y * exp2f((e.x - m) * LOG2E);
  const float inv = 1.f / l;
  const float mh  = m * LOG2E;
  float4* p = (float4*)(attn0 + (size_t)row * L_);
#pragma unroll
  for (int i = 0; i < 2; ++i) {
    const int idx = threadIdx.x + i * 256;
    float4 v = p[idx];
    v.x = exp2f(fmaf(v.x, LOG2E, -mh)) * inv;
    v.y = exp2f(fmaf(v.y, LOG2E, -mh)) * inv;
    v.z = exp2f(fmaf(v.z, LOG2E, -mh)) * inv;
    v.w = exp2f(fmaf(v.w, LOG2E, -mh)) * inv;
    p[idx] = v;
  }
}

extern "C" void kernel_launch(void* const* d_in, const int* in_sizes, int n_in,
                              void* d_out, int out_size, void* d_ws, size_t ws_size,
                              hipStream_t stream) {
  const float* Q    = (const float*)d_in[0];
  const float* K    = (const float*)d_in[1];
  const float* V    = (const float*)d_in[2];
  const float* bias = (const float*)d_in[3];
  float* ctx   = (float*)d_out;
  float* attn0 = ctx + (size_t)B_ * L_ * D_;

  const size_t kvElems  = (size_t)B_ * L_ * D_;              // 8.39M
  const size_t imgBytes = 2 * kvElems * sizeof(__bf16);      // 33.6 MB
  const size_t opBytes  = 2 * kvElems * sizeof(float);       // 67.1 MB
  const size_t mlBytes  = (size_t)2 * B_ * L_ * sizeof(float2);  // 1.05 MB

  __bf16* gK    = (__bf16*)d_ws;
  __bf16* gVt   = gK + kvElems;
  float*  Opart = (float*)(gVt + kvElems);
  float2* ml    = (float2*)(Opart + 2 * kvElems);

  if (ws_size >= imgBytes + opBytes + mlBytes) {
    prep_kv<<<dim3(B_ * NT_), 256, 0, stream>>>(K, V, gK, gVt);
    attn_fwd<1, 1><<<dim3(1024), 256, 0, stream>>>(Q, K, V, bias, gK, gVt,
                                                   ctx, attn0, Opart, ml);
    combine<<<dim3(B_ * L_ / 8), 256, 0, stream>>>(Opart, ml, ctx);
    attn0_norm<<<dim3(L_), 256, 0, stream>>>(attn0, ml);
  } else if (ws_size >= imgBytes) {
    prep_kv<<<dim3(B_ * NT_), 256, 0, stream>>>(K, V, gK, gVt);
    attn_fwd<0, 1><<<dim3(512), 256, 0, stream>>>(Q, K, V, bias, gK, gVt,
                                                  ctx, attn0, nullptr, nullptr);
  } else {
    attn_fwd<0, 0><<<dim3(512), 256, 0, stream>>>(Q, K, V, bias, nullptr, nullptr,
                                                  ctx, attn0, nullptr, nullptr);
  }
}

// Round 12
// 148.748 us; speedup vs baseline: 3.7340x; 3.7340x over previous
//
#include <hip/hip_runtime.h>
#include <cstdint>
#include <cstddef>

#define L_ 2048
#define D_ 128
#define B_ 32
#define NT_ 32   // kv tiles of 64

static constexpr float SCALE = 0.08838834764831845f;  // 1/sqrt(128)
static constexpr float LOG2E = 1.4426950408889634f;
static constexpr float THR_  = 8.0f;                  // defer-rescale threshold

typedef __bf16 bf16x8 __attribute__((ext_vector_type(8)));
typedef __bf16 bf16x4 __attribute__((ext_vector_type(4)));
typedef float  f32x4  __attribute__((ext_vector_type(4)));
typedef int    i32x4  __attribute__((ext_vector_type(4)));

typedef const __attribute__((address_space(1))) uint32_t* gas_t;
typedef __attribute__((address_space(3))) uint32_t*       las_t;

__device__ __forceinline__ void dma16(const void* g, void* l) {
  // LDS dest is wave-uniform base; HW adds lane*16. size must be literal 16.
  __builtin_amdgcn_global_load_lds((gas_t)g, (las_t)l, 16, 0, 0);
}

// PV k-permutation (validated r8): P stays in registers (lane owns
// P[q=lr][kv=t*16+lg*4+j]); V image columns permuted so the A-fragment slot
// k=lg*8+j holds kv = kc2*32 + pi(k). V row r lands at column cperm(r).
__device__ __forceinline__ int cperm(int r) {
  return (r & 32) | (((r >> 3) & 1) << 4) | (((r >> 2) & 1) << 3)
       | (((r >> 4) & 1) << 2) | (r & 3);
}

// ---------------------------------------------------------------------------
// prep_kv: bf16 K (QK-swizzled) and V^T (cperm + swizzle) tile images so a
// linear DMA into LDS reproduces the layouts attn reads. grid 1024 x 256.
// ---------------------------------------------------------------------------
__global__ __launch_bounds__(256) void prep_kv(
    const float* __restrict__ K, const float* __restrict__ V,
    __bf16* __restrict__ gK, __bf16* __restrict__ gVt)
{
  const int b   = blockIdx.x >> 5;
  const int kt  = blockIdx.x & 31;
  const int tid = threadIdx.x;
  const size_t tile = ((size_t)b * NT_ + kt) * 8192;

#pragma unroll
  for (int i = 0; i < 4; ++i) {
    const int g  = tid + i * 256;
    const int r  = g >> 4;
    const int c  = g & 15;
    const int d0 = (c ^ (r & 7)) * 8;
    const float* src = K + ((size_t)b * L_ + kt * 64 + r) * D_ + d0;
    float4 a = *(const float4*)src;
    float4 e = *(const float4*)(src + 4);
    bf16x8 f;
    f[0]=(__bf16)a.x; f[1]=(__bf16)a.y; f[2]=(__bf16)a.z; f[3]=(__bf16)a.w;
    f[4]=(__bf16)e.x; f[5]=(__bf16)e.y; f[6]=(__bf16)e.z; f[7]=(__bf16)e.w;
    *(bf16x8*)((char*)(gK + tile) + r * 256 + c * 16) = f;
  }

  __shared__ alignas(16) __bf16 Vt[8192];
  char* vb = (char*)Vt;
  const int vr     = tid & 63;
  const int vc     = cperm(vr);
  const int vdbase = (tid >> 6) * 32;
  const float* vrow = V + ((size_t)b * L_ + kt * 64 + vr) * D_ + vdbase;
#pragma unroll
  for (int c = 0; c < 8; ++c) {
    float4 v4 = *(const float4*)(vrow + c * 4);
    const int d0 = vdbase + c * 4;
    float vv[4] = {v4.x, v4.y, v4.z, v4.w};
#pragma unroll
    for (int jj = 0; jj < 4; ++jj) {
      const int d = d0 + jj;
      *(__bf16*)(vb + d * 128 + ((vc * 2) ^ ((d & 7) << 4))) = (__bf16)vv[jj];
    }
  }
  __syncthreads();
#pragma unroll
  for (int i = 0; i < 4; ++i) {
    const int off = (tid + i * 256) * 16;
    *(i32x4*)((char*)(gVt + tile) + off) = *(const i32x4*)(vb + off);
  }
}

// ---------------------------------------------------------------------------
// attn_fwd<MODE>: consolidation of the best-measured structure (r6, 144.8us)
// + zero-shuffle PV (r8) + raw-bias fmaf:
//   swapped QK^T (S^T = mfma(K,Q)), lane owns one q-row (q=lr);
//   512 threads (8 waves x 16 q-rows), QBLK=128, grid 512;
//   r6 XCD mapping: 4 batches per XCD (b = (id&7)*4 + ...);
//   single 32KB K/V LDS buffer -> 2 blocks/CU = 16 waves/CU (cache-feasible:
//   64 blocks/XCD x 32KB streams ~ 4MB L2 -- the r11 lesson);
//   r6 schedule: [barrier(drains DMA)] bias,QK,z,softmax,PV [barrier] stage(kt+1).
//   MODE 1: DMA staging from prepped images.  MODE 0: in-kernel staging.
// ---------------------------------------------------------------------------
template<int MODE>
__global__ __launch_bounds__(512, 4) void attn_fwd(
    const float* __restrict__ Q, const float* __restrict__ K,
    const float* __restrict__ V, const float* __restrict__ bias,
    const __bf16* __restrict__ gK, const __bf16* __restrict__ gVt,
    float* __restrict__ ctx, float* __restrict__ attn0)
{
  const int id   = blockIdx.x;
  const int idx  = id >> 3;
  const int b    = (id & 7) * 4 + (idx >> 4);
  const int qblk = idx & 15;

  const int tid  = threadIdx.x;
  const int wave = tid >> 6;
  const int lane = tid & 63;
  const int lg   = lane >> 4;   // 0..3
  const int lr   = lane & 15;   // 0..15

  const int qbase = qblk * 128 + wave * 16;

  __shared__ alignas(16) __bf16 Ksh[8192];    // 16 KB single buffer
  __shared__ alignas(16) __bf16 Vtsh[8192];   // 16 KB single buffer
  const char* kb = (const char*)Ksh;
  const char* vb = (const char*)Vtsh;

  // ---- Q fragments, pre-scaled (B operand): SCALE*Q[qbase+lr][kc*32+lg*8+j]
  bf16x8 qf[4];
  {
    const float* qrow = Q + ((size_t)b * L_ + (qbase + lr)) * D_;
#pragma unroll
    for (int kc = 0; kc < 4; ++kc) {
      const int d0 = kc * 32 + lg * 8;
      float4 a = *(const float4*)(qrow + d0);
      float4 c = *(const float4*)(qrow + d0 + 4);
      bf16x8 f;
      f[0] = (__bf16)(a.x * SCALE); f[1] = (__bf16)(a.y * SCALE);
      f[2] = (__bf16)(a.z * SCALE); f[3] = (__bf16)(a.w * SCALE);
      f[4] = (__bf16)(c.x * SCALE); f[5] = (__bf16)(c.y * SCALE);
      f[6] = (__bf16)(c.z * SCALE); f[7] = (__bf16)(c.w * SCALE);
      qf[kc] = f;
    }
  }

  f32x4 Oacc[8];
#pragma unroll
  for (int i = 0; i < 8; ++i) Oacc[i] = (f32x4){0.f, 0.f, 0.f, 0.f};
  float m_run = -3.0e38f;   // running max for q-row lr (same in all 4 lg lanes)
  float lp    = 0.f;        // per-lane partial denominator for q-row lr

  // DMA staging: per wave 2 K-chunks + 2 V-chunks of 1KB = 4 vmem instrs/thread.
  auto stage_dma = [&](int kt) {
    const char* gk = (const char*)(gK + ((size_t)b * NT_ + kt) * 8192);
    const char* gv = (const char*)(gVt + ((size_t)b * NT_ + kt) * 8192);
#pragma unroll
    for (int i = 0; i < 2; ++i) {
      const int off = (wave * 2 + i) * 1024;
      dma16(gk + off + lane * 16, (char*)Ksh + off);
      dma16(gv + off + lane * 16, (char*)Vtsh + off);
    }
  };

  if constexpr (MODE >= 1) stage_dma(0);

  for (int kt = 0; kt < NT_; ++kt) {
    const int kvbase = kt * 64;

    if constexpr (MODE == 0) {
      // in-kernel staging (prev end-barrier protects the buffer)
#pragma unroll
      for (int it = 0; it < 4; ++it) {
        const int g  = tid + it * 512;   // float4 group 0..2047
        const int r  = g >> 5;
        const int d0 = (g & 31) * 4;
        const size_t src = ((size_t)b * L_ + (kvbase + r)) * D_ + d0;
        float4 kv4 = *(const float4*)(K + src);
        bf16x4 k4 = {(__bf16)kv4.x, (__bf16)kv4.y, (__bf16)kv4.z, (__bf16)kv4.w};
        *(bf16x4*)((char*)Ksh + r * 256 + ((d0 * 2) ^ ((r & 7) << 4))) = k4;
      }
      {
        const int vr = tid & 63;
        const int vc = cperm(vr);
        const int vdbase = (tid >> 6) * 16;
        const float* vrow = V + ((size_t)b * L_ + (kvbase + vr)) * D_ + vdbase;
#pragma unroll
        for (int c = 0; c < 4; ++c) {
          float4 v4 = *(const float4*)(vrow + c * 4);
          const int d0 = vdbase + c * 4;
          float vv[4] = {v4.x, v4.y, v4.z, v4.w};
#pragma unroll
          for (int jj = 0; jj < 4; ++jj) {
            const int d = d0 + jj;
            *(__bf16*)((char*)Vtsh + d * 128 + ((vc * 2) ^ ((d & 7) << 4))) = (__bf16)vv[jj];
          }
        }
      }
    }
    // drains own DMA (syncthreads' vmcnt(0)) / completes in-kernel staging
    __syncthreads();

    // ---- bias loads early (consumed after MFMA -> latency hidden) ----
    float4 bf4[4];
    {
      const float* bp = bias + (size_t)(qbase + lr) * L_ + kvbase + lg * 4;
#pragma unroll
      for (int t = 0; t < 4; ++t) bf4[t] = *(const float4*)(bp + t * 16);
    }

    // ---- S^T = K . (SCALE*Q)^T : Sacc[t] row=kv(t*16+lg*4+j), col=q(lr) ----
    f32x4 Sacc[4];
#pragma unroll
    for (int t = 0; t < 4; ++t) Sacc[t] = (f32x4){0.f, 0.f, 0.f, 0.f};
    __builtin_amdgcn_s_setprio(1);
#pragma unroll
    for (int t = 0; t < 4; ++t) {
      const int r   = t * 16 + lr;
      const int swz = (r & 7) << 4;
#pragma unroll
      for (int kc = 0; kc < 4; ++kc) {
        const int d0 = kc * 32 + lg * 8;
        bf16x8 kf = *(const bf16x8*)(kb + r * 256 + ((d0 * 2) ^ swz));
        Sacc[t] = __builtin_amdgcn_mfma_f32_16x16x32_bf16(kf, qf[kc], Sacc[t], 0, 0, 0);
      }
    }
    __builtin_amdgcn_s_setprio(0);

    // ---- z = S + bias*SCALE (fmaf folds SCALE; no prepped bias) ----
    float zz[4][4];
#pragma unroll
    for (int t = 0; t < 4; ++t) {
      zz[t][0] = fmaf(bf4[t].x, SCALE, Sacc[t][0]);
      zz[t][1] = fmaf(bf4[t].y, SCALE, Sacc[t][1]);
      zz[t][2] = fmaf(bf4[t].z, SCALE, Sacc[t][2]);
      zz[t][3] = fmaf(bf4[t].w, SCALE, Sacc[t][3]);
    }
    if (b == 0) {
      float* ap = attn0 + (size_t)(qbase + lr) * L_ + kvbase + lg * 4;
#pragma unroll
      for (int t = 0; t < 4; ++t)
        *(float4*)(ap + t * 16) = make_float4(zz[t][0], zz[t][1], zz[t][2], zz[t][3]);
    }

    // ---- online softmax: row max (2 shuffles), defer-rescale, per-lane lp ----
    float mt = fmaxf(fmaxf(fmaxf(zz[0][0], zz[0][1]), fmaxf(zz[0][2], zz[0][3])),
                     fmaxf(fmaxf(zz[1][0], zz[1][1]), fmaxf(zz[1][2], zz[1][3])));
    mt = fmaxf(mt, fmaxf(fmaxf(zz[2][0], zz[2][1]), fmaxf(zz[2][2], zz[2][3])));
    mt = fmaxf(mt, fmaxf(fmaxf(zz[3][0], zz[3][1]), fmaxf(zz[3][2], zz[3][3])));
    mt = fmaxf(mt, __shfl_xor(mt, 16));
    mt = fmaxf(mt, __shfl_xor(mt, 32));

    if (__any(mt > m_run + THR_)) {
      const float mnew = fmaxf(m_run, mt);
      const float corr = exp2f((m_run - mnew) * LOG2E);
      m_run = mnew;
      lp *= corr;
      float cR[4];
#pragma unroll
      for (int j = 0; j < 4; ++j)
        cR[j] = __shfl(corr, (lane & 0x30) | (lg * 4 + j));
#pragma unroll
      for (int dt = 0; dt < 8; ++dt) {
        Oacc[dt][0] *= cR[0]; Oacc[dt][1] *= cR[1];
        Oacc[dt][2] *= cR[2]; Oacc[dt][3] *= cR[3];
      }
    }

    // ---- P = exp(z - m) as bf16, kept in registers ----
    bf16x4 pbf[4];
    const float mh = m_run * LOG2E;
#pragma unroll
    for (int t = 0; t < 4; ++t) {
#pragma unroll
      for (int j = 0; j < 4; ++j) {
        const float p = exp2f(fmaf(zz[t][j], LOG2E, -mh));
        lp += p;
        pbf[t][j] = (__bf16)p;
      }
    }

    // ---- O += P . V  (pa = own registers; V image k-permuted to match) ----
    __builtin_amdgcn_s_setprio(1);
#pragma unroll
    for (int kc2 = 0; kc2 < 2; ++kc2) {
      bf16x8 pa;
      pa[0] = pbf[kc2 * 2][0];     pa[1] = pbf[kc2 * 2][1];
      pa[2] = pbf[kc2 * 2][2];     pa[3] = pbf[kc2 * 2][3];
      pa[4] = pbf[kc2 * 2 + 1][0]; pa[5] = pbf[kc2 * 2 + 1][1];
      pa[6] = pbf[kc2 * 2 + 1][2]; pa[7] = pbf[kc2 * 2 + 1][3];
      const int c0 = kc2 * 32;
#pragma unroll
      for (int dt = 0; dt < 8; ++dt) {
        const int d = dt * 16 + lr;
        bf16x8 vf = *(const bf16x8*)(vb + d * 128 + (((c0 + lg * 8) * 2) ^ ((d & 7) << 4)));
        Oacc[dt] = __builtin_amdgcn_mfma_f32_16x16x32_bf16(pa, vf, Oacc[dt], 0, 0, 0);
      }
    }
    __builtin_amdgcn_s_setprio(0);

    // all reads of Ksh/Vtsh done -> safe to restage (drained at next top barrier)
    __syncthreads();
    if constexpr (MODE >= 1) {
      if (kt + 1 < NT_) stage_dma(kt + 1);
    }
  }

  // ---- epilogue: full row sum, redistribute inverse to Oacc rows ----
  float ls = lp;
  ls += __shfl_xor(ls, 16);
  ls += __shfl_xor(ls, 32);
  const float linv = 1.f / ls;
  float invR[4];
#pragma unroll
  for (int j = 0; j < 4; ++j)
    invR[j] = __shfl(linv, (lane & 0x30) | (lg * 4 + j));
#pragma unroll
  for (int dt = 0; dt < 8; ++dt) {
    const int d = dt * 16 + lr;
#pragma unroll
    for (int j = 0; j < 4; ++j) {
      const int q = qbase + lg * 4 + j;
      ctx[((size_t)b * L_ + q) * D_ + d] = Oacc[dt][j] * invR[j];
    }
  }
}

// ---------------------------------------------------------------------------
// softmax_rows: in-place row softmax of attn0 (batch-0 raw scaled scores).
// Separate balanced dispatch (fusing into b==0 blocks measured -25us, r10).
// ---------------------------------------------------------------------------
__global__ __launch_bounds__(256) void softmax_rows(float* __restrict__ attn0)
{
  const int row  = blockIdx.x;
  float* p = attn0 + (size_t)row * L_;
  const int tid  = threadIdx.x;
  const int wave = tid >> 6;
  const int lane = tid & 63;
  __shared__ float red[8];

  float4 a = ((const float4*)p)[tid];
  float4 c = ((const float4*)p)[tid + 256];
  float v[8] = {a.x, a.y, a.z, a.w, c.x, c.y, c.z, c.w};

  float mx = v[0];
#pragma unroll
  for (int i = 1; i < 8; ++i) mx = fmaxf(mx, v[i]);
#pragma unroll
  for (int msk = 1; msk < 64; msk <<= 1) mx = fmaxf(mx, __shfl_xor(mx, msk));
  if (lane == 0) red[wave] = mx;
  __syncthreads();
  mx = fmaxf(fmaxf(red[0], red[1]), fmaxf(red[2], red[3]));

  float e[8];
  float s = 0.f;
#pragma unroll
  for (int i = 0; i < 8; ++i) { e[i] = exp2f((v[i] - mx) * LOG2E); s += e[i]; }
#pragma unroll
  for (int msk = 1; msk < 64; msk <<= 1) s += __shfl_xor(s, msk);
  if (lane == 0) red[4 + wave] = s;
  __syncthreads();
  s = red[4] + red[5] + red[6] + red[7];
  const float inv = 1.f / s;

  float4 o0 = {e[0] * inv, e[1] * inv, e[2] * inv, e[3] * inv};
  float4 o1 = {e[4] * inv, e[5] * inv, e[6] * inv, e[7] * inv};
  ((float4*)p)[tid]       = o0;
  ((float4*)p)[tid + 256] = o1;
}

extern "C" void kernel_launch(void* const* d_in, const int* in_sizes, int n_in,
                              void* d_out, int out_size, void* d_ws, size_t ws_size,
                              hipStream_t stream) {
  const float* Q    = (const float*)d_in[0];
  const float* K    = (const float*)d_in[1];
  const float* V    = (const float*)d_in[2];
  const float* bias = (const float*)d_in[3];
  float* ctx   = (float*)d_out;
  float* attn0 = ctx + (size_t)B_ * L_ * D_;

  const size_t kvElems = (size_t)B_ * L_ * D_;           // per image
  const size_t needKV  = 2 * kvElems * sizeof(__bf16);   // 33.6 MB

  __bf16* gK  = (__bf16*)d_ws;
  __bf16* gVt = gK + kvElems;

  if (ws_size >= needKV) {
    prep_kv<<<dim3(B_ * NT_), 256, 0, stream>>>(K, V, gK, gVt);
    attn_fwd<1><<<dim3(512), 512, 0, stream>>>(Q, K, V, bias, gK, gVt, ctx, attn0);
  } else {
    attn_fwd<0><<<dim3(512), 512, 0, stream>>>(Q, K, V, bias, nullptr, nullptr, ctx, attn0);
  }
  softmax_rows<<<L_, 256, 0, stream>>>(attn0);
}